// Round 1
// baseline (543.523 us; speedup 1.0000x reference)
//
#include <hip/hip_runtime.h>
#include <hip/hip_bf16.h>

// Problem constants
#define TB 128
#define TT 500
#define TS 200
#define TE 100
#define TH 100
#define NCLS 400              // 2*S  (one-hot width of x)
#define NG   400              // 4*H  (gate width)
#define BT   (TB*TT)          // 64000 (b,t) pairs

__device__ __forceinline__ float fsig(float x) { return 1.0f / (1.0f + __expf(-x)); }
__device__ __forceinline__ float ftanh(float x) { float e = __expf(2.0f * x); return 1.0f - 2.0f / (e + 1.0f); }

// ---------------------------------------------------------------------------
// Kernel A: compress one-hot x (B,T,400) -> idx2 (class in [0,400)) and
//           one-hot q (B,T,200) -> qi (in [0,200)). One wave per (b,t).
// ---------------------------------------------------------------------------
__global__ void k_compress(const float* __restrict__ x, const float* __restrict__ q,
                           int* __restrict__ idx2, int* __restrict__ qi) {
  int gid  = blockIdx.x * blockDim.x + threadIdx.x;
  int wave = gid >> 6;
  int lane = threadIdx.x & 63;
  if (wave >= BT) return;

  // x row: 400 floats = 100 float4; lanes 0..63 then 0..35 take chunks 64..99
  const float4* xr = (const float4*)(x + (size_t)wave * NCLS);
  int li = -1;
  {
    float4 v = xr[lane];
    if (v.x > 0.5f) li = lane * 4 + 0;
    if (v.y > 0.5f) li = lane * 4 + 1;
    if (v.z > 0.5f) li = lane * 4 + 2;
    if (v.w > 0.5f) li = lane * 4 + 3;
    int ci = 64 + lane;
    if (ci < 100) {
      float4 w = xr[ci];
      if (w.x > 0.5f) li = ci * 4 + 0;
      if (w.y > 0.5f) li = ci * 4 + 1;
      if (w.z > 0.5f) li = ci * 4 + 2;
      if (w.w > 0.5f) li = ci * 4 + 3;
    }
  }
  #pragma unroll
  for (int off = 32; off; off >>= 1) li = max(li, __shfl_xor(li, off));

  // q row: 200 floats = 50 float4
  const float4* qr = (const float4*)(q + (size_t)wave * TS);
  int qj = -1;
  if (lane < 50) {
    float4 v = qr[lane];
    if (v.x > 0.5f) qj = lane * 4 + 0;
    if (v.y > 0.5f) qj = lane * 4 + 1;
    if (v.z > 0.5f) qj = lane * 4 + 2;
    if (v.w > 0.5f) qj = lane * 4 + 3;
  }
  #pragma unroll
  for (int off = 32; off; off >>= 1) qj = max(qj, __shfl_xor(qj, off));

  if (lane == 0) { idx2[wave] = li; qi[wave] = qj; }
}

// ---------------------------------------------------------------------------
// Kernel B: precompute
//   G[c][j]    = sum_e Wx[c][e] * K[e][j]                  (400x400)
//   base[j]    = sum_e bx[e] * K[e][j] + lstm_b[j]         (400)
//   crow0[j]   = K[100][j] + K[102][j]   (cc coefficient)
//   crow1[j]   = K[101][j] + K[102][j]   (ic coefficient)
//   WoT[s][k]  = Wo[k][s]                                  (200x100)
// ---------------------------------------------------------------------------
__global__ void k_precompute(const float* __restrict__ Wx, const float* __restrict__ bx,
                             const float* __restrict__ K, const float* __restrict__ lb,
                             const float* __restrict__ Wo,
                             float* __restrict__ G, float* __restrict__ base,
                             float* __restrict__ crow0, float* __restrict__ crow1,
                             float* __restrict__ WoT) {
  int bid = blockIdx.x, tid = threadIdx.x;
  if (bid < NCLS) {
    if (tid < NG) {
      float acc = 0.0f;
      for (int e = 0; e < TE; ++e) acc = fmaf(Wx[bid * TE + e], K[e * NG + tid], acc);
      G[bid * NG + tid] = acc;
    }
  } else if (bid == NCLS) {
    if (tid < NG) {
      float acc = lb[tid];
      for (int e = 0; e < TE; ++e) acc = fmaf(bx[e], K[e * NG + tid], acc);
      base[tid]  = acc;
      crow0[tid] = K[100 * NG + tid] + K[102 * NG + tid];
      crow1[tid] = K[101 * NG + tid] + K[102 * NG + tid];
    }
  } else {
    int id = (bid - NCLS - 1) * 512 + tid;
    if (id < TS * TH) {
      int s = id / TH, k = id % TH;
      WoT[id] = Wo[k * TS + s];
    }
  }
}

// ---------------------------------------------------------------------------
// Kernel C: the LSTM recurrence + count-feature scan. One block per batch b.
// Threads 0..399 each own one gate-column j of lstm_rk (100 VGPRs).
// h lives in LDS (lane-uniform broadcast float4 reads). Thread 0 maintains
// the per-class running counts (the count scan is sequential anyway).
// ---------------------------------------------------------------------------
__global__ void __launch_bounds__(512) k_lstm(const int* __restrict__ idx2,
                                              const float* __restrict__ G,
                                              const float* __restrict__ base,
                                              const float* __restrict__ crow0,
                                              const float* __restrict__ crow1,
                                              const float* __restrict__ R,   // lstm_rk (100x400)
                                              float* __restrict__ h_seq) {   // (B,T,100)
  int b = blockIdx.x;
  int tid = threadIdx.x;

  __shared__ __align__(16) float h_s[TH];
  __shared__ float cnt[NCLS];
  __shared__ float ccic[2];
  __shared__ float zs[NG];

  // init
  for (int i = tid; i < NCLS; i += 512) cnt[i] = 0.0f;
  if (tid < TH) h_s[tid] = 0.0f;
  float c_reg = 0.0f;

  // preload column tid of R and the per-column constants
  float r[TH];
  float basej = 0.0f, c0j = 0.0f, c1j = 0.0f;
  if (tid < NG) {
    #pragma unroll
    for (int k = 0; k < TH; ++k) r[k] = R[k * NG + tid];
    basej = base[tid]; c0j = crow0[tid]; c1j = crow1[tid];
  }
  __syncthreads();

  const int* idxb = idx2 + (size_t)b * TT;
  float* hout = h_seq + (size_t)b * TT * TH;

  for (int t = 0; t < TT; ++t) {
    int cls = idxb[t];
    if (tid == 0) {
      float n0 = cnt[cls] + 1.0f;
      cnt[cls] = n0;
      int s2 = cls & ~1;
      ccic[0] = __logf(1.0f + cnt[s2]);
      ccic[1] = __logf(1.0f + cnt[s2 + 1]);
    }
    __syncthreads();   // cc/ic ready; h_s from previous step visible

    if (tid < NG) {
      float cc = ccic[0], ic = ccic[1];
      float z = basej + cc * c0j + ic * c1j + G[(size_t)cls * NG + tid];
      const float4* h4 = (const float4*)h_s;
      float a0 = 0.f, a1 = 0.f, a2 = 0.f, a3 = 0.f;
      #pragma unroll
      for (int k4 = 0; k4 < TH / 4; ++k4) {
        float4 hv = h4[k4];                 // lane-uniform broadcast read
        a0 = fmaf(hv.x, r[4 * k4 + 0], a0);
        a1 = fmaf(hv.y, r[4 * k4 + 1], a1);
        a2 = fmaf(hv.z, r[4 * k4 + 2], a2);
        a3 = fmaf(hv.w, r[4 * k4 + 3], a3);
      }
      zs[tid] = z + ((a0 + a1) + (a2 + a3));
    }
    __syncthreads();   // all gates ready

    if (tid < TH) {
      float zi = zs[tid], zf = zs[tid + TH], zg = zs[tid + 2 * TH], zo = zs[tid + 3 * TH];
      c_reg = fsig(zf) * c_reg + fsig(zi) * ftanh(zg);
      float hn = fsig(zo) * ftanh(c_reg);
      h_s[tid] = hn;
      hout[(size_t)t * TH + tid] = hn;
    }
    // next iteration's first barrier orders h_s write vs. z-phase reads,
    // and zs reads (this phase) vs. zs writes (next z-phase).
  }
}

// ---------------------------------------------------------------------------
// Kernel D: out[b,t] = sigmoid( h_seq[b,t] . WoT[qi[b,t]] + bo[qi] )
// One wave per (b,t).
// ---------------------------------------------------------------------------
__global__ void k_out(const float* __restrict__ h_seq, const float* __restrict__ WoT,
                      const float* __restrict__ bo, const int* __restrict__ qi,
                      float* __restrict__ out) {
  int gid  = blockIdx.x * blockDim.x + threadIdx.x;
  int wave = gid >> 6;
  int lane = threadIdx.x & 63;
  if (wave >= BT) return;
  int s = qi[wave];
  const float4* h4 = (const float4*)(h_seq + (size_t)wave * TH);
  const float4* w4 = (const float4*)(WoT + (size_t)s * TH);
  float acc = 0.0f;
  if (lane < TH / 4) {
    float4 h = h4[lane];
    float4 w = w4[lane];
    acc = h.x * w.x + h.y * w.y + h.z * w.z + h.w * w.w;
  }
  #pragma unroll
  for (int off = 32; off; off >>= 1) acc += __shfl_xor(acc, off);
  if (lane == 0) out[wave] = fsig(acc + bo[s]);
}

// ---------------------------------------------------------------------------
extern "C" void kernel_launch(void* const* d_in, const int* in_sizes, int n_in,
                              void* d_out, int out_size, void* d_ws, size_t ws_size,
                              hipStream_t stream) {
  const float* x    = (const float*)d_in[0];
  // d_in[1] = delta (unused by the reference)
  const float* q    = (const float*)d_in[2];
  const float* Wx   = (const float*)d_in[3];
  const float* bx   = (const float*)d_in[4];
  const float* K    = (const float*)d_in[5];   // lstm_k (103,400)
  const float* R    = (const float*)d_in[6];   // lstm_rk (100,400)
  const float* lb   = (const float*)d_in[7];   // lstm_b (400)
  const float* Wo   = (const float*)d_in[8];   // (100,200)
  const float* bo   = (const float*)d_in[9];   // (200)
  float* out = (float*)d_out;

  // workspace layout (floats)
  float* ws = (float*)d_ws;
  float* G      = ws;                 // 160000
  float* base   = ws + 160000;        // 400
  float* crow0  = ws + 160400;        // 400
  float* crow1  = ws + 160800;        // 400
  float* WoT    = ws + 161200;        // 20000
  int*   idx2   = (int*)(ws + 181200);// 64000
  int*   qi     = (int*)(ws + 245200);// 64000
  float* h_seq  = ws + 309200;        // 6,400,000
  // total: 6,709,200 floats = 26.8 MB

  // A: compress one-hots (memory-bound, independent of B)
  k_compress<<<BT / 4, 256, 0, stream>>>(x, q, idx2, qi);

  // B: precompute tables (tiny)
  int wot_blocks = (TS * TH + 511) / 512;                // 40
  k_precompute<<<NCLS + 1 + wot_blocks, 512, 0, stream>>>(Wx, bx, K, lb, Wo,
                                                          G, base, crow0, crow1, WoT);

  // C: sequential LSTM, one block per batch element
  k_lstm<<<TB, 512, 0, stream>>>(idx2, G, base, crow0, crow1, R, h_seq);

  // D: gather + dot + sigmoid
  k_out<<<BT / 4, 256, 0, stream>>>(h_seq, WoT, bo, qi, out);
}